// Round 10
// baseline (264.396 us; speedup 1.0000x reference)
//
#include <hip/hip_runtime.h>
#include <hip/hip_bf16.h>

// Problem constants
#define B_  16
#define T_  1024
#define C_  1024
#define H_  16
#define KW_ 31
#define M_  (B_ * T_)     // 16384 rows
#define N1_ (2 * C_)      // 2048  (GEMM1 N)
#define K1_ C_            // 1024  (GEMM1 K)
#define N2_ C_            // 1024  (GEMM2 N)
#define K2_ (2 * C_)      // 2048  (GEMM2 K)

typedef __attribute__((ext_vector_type(8))) short bf16x8;
typedef __attribute__((ext_vector_type(4))) short s16x4;
typedef __attribute__((ext_vector_type(4))) float f32x4;

typedef const __attribute__((address_space(1))) void GV;
typedef __attribute__((address_space(3))) void LV;

__device__ __forceinline__ short f2bf(float f) {
  union { float f; unsigned u; } v; v.f = f;
  unsigned r = v.u + 0x7fffu + ((v.u >> 16) & 1u);   // RNE
  return (short)(r >> 16);
}
__device__ __forceinline__ float b2f(short s) {
  union { float f; unsigned u; } v;
  v.u = ((unsigned)(unsigned short)s) << 16;
  return v.f;
}

// ---------------------------------------------------------------------------
// softmax over the 31-tap kernels: rows 0..15 = weight[h], row 16 = weight_f
__global__ void softmax_w(const float* __restrict__ w,
                          const float* __restrict__ wf,
                          float* __restrict__ wsm) {
  int t = threadIdx.x;
  if (t >= 17) return;
  const float* src = (t < 16) ? (w + t * KW_) : wf;
  float mx = -1e30f;
  #pragma unroll
  for (int k = 0; k < KW_; ++k) mx = fmaxf(mx, src[k]);
  float e[KW_], s = 0.f;
  #pragma unroll
  for (int k = 0; k < KW_; ++k) { e[k] = __expf(src[k] - mx); s += e[k]; }
  float inv = 1.f / s;
  #pragma unroll
  for (int k = 0; k < KW_; ++k) wsm[t * KW_ + k] = e[k] * inv;
}

// ---------------------------------------------------------------------------
// fp32 -> bf16 convert, vectorized x4
__global__ void cvt_bf16(const float* __restrict__ in, short* __restrict__ out, int n4) {
  int i = blockIdx.x * blockDim.x + threadIdx.x;
  if (i >= n4) return;
  float4 f = ((const float4*)in)[i];
  s16x4 s = { f2bf(f.x), f2bf(f.y), f2bf(f.z), f2bf(f.w) };
  ((s16x4*)out)[i] = s;
}

// W1 (2048x1024 fp32) -> W1b bf16 with ROW INTERLEAVE: row 2j = W1[j] (a), row 2j+1 = W1[1024+j] (g)
__global__ void cvt_w1i(const float* __restrict__ W1, short* __restrict__ W1b) {
  int idx = blockIdx.x * blockDim.x + threadIdx.x;  // 2048*1024/8 threads
  int r = idx >> 7;
  int c = (idx & 127) * 8;
  int s = (r & 1) ? (1024 + (r >> 1)) : (r >> 1);
  const float* src = W1 + (long)s * 1024 + c;
  bf16x8 o;
  #pragma unroll
  for (int i = 0; i < 8; ++i) o[i] = f2bf(src[i]);
  *(bf16x8*)(W1b + (long)r * 1024 + c) = o;
}

// copy W2[:, 0:1024] (fp32) -> W2b[:, 0:1024] (bf16), row stride 2048 both sides
__global__ void cvt_w2c(const float* __restrict__ W2, short* __restrict__ W2b) {
  int i = blockIdx.x * blockDim.x + threadIdx.x;   // over 1024*1024/4
  int o  = i >> 8;
  int c4 = (i & 255) * 4;
  float4 f = *(const float4*)(W2 + (long)o * K2_ + c4);
  s16x4 s = { f2bf(f.x), f2bf(f.y), f2bf(f.z), f2bf(f.w) };
  *(s16x4*)(W2b + (long)o * K2_ + c4) = s;
}

// fold the feature-axis conv into W2's second half:
// W2fold[o,j] = sum_k wf[k] * W2[o, 1024 + (j+15-k)]   (valid c only)
__global__ void fold_w2f(const float* __restrict__ W2,
                         const float* __restrict__ wsm,
                         short* __restrict__ W2b) {
  int idx = blockIdx.x * blockDim.x + threadIdx.x;   // over 1024*1024
  int o = idx >> 10, j = idx & 1023;
  const float* base = W2 + (long)o * K2_ + C_;
  float s = 0.f;
  #pragma unroll
  for (int k = 0; k < KW_; ++k) {
    int c = j + 15 - k;
    if (c >= 0 && c < C_) s += wsm[16 * KW_ + k] * base[c];
  }
  W2b[(long)o * K2_ + C_ + j] = f2bf(s);
}

// ---------------------------------------------------------------------------
// depthwise conv over time: xc[b,t,c] = sum_k w[c%16,k] * x[b,t+k-15,c]
__global__ __launch_bounds__(256) void conv_t_k(const short* __restrict__ A2in,
                                                const float* __restrict__ wsm,
                                                short* __restrict__ A2out) {
  const int tid = threadIdx.x;
  const int t0  = blockIdx.x * 128;
  const int c   = blockIdx.y * 256 + tid;
  const int b   = blockIdx.z;
  const int h   = c & (H_ - 1);

  float wk[KW_];
  #pragma unroll
  for (int k = 0; k < KW_; ++k) wk[k] = wsm[h * KW_ + k];

  const long rowbase = ((long)b * T_) * K2_ + C_ + c;
  float win[KW_];
  #pragma unroll
  for (int k = 0; k < 30; ++k) {
    int t = t0 - 15 + k;
    win[k] = (t >= 0 && t < T_) ? b2f(A2in[rowbase + (long)t * K2_]) : 0.f;
  }
  for (int tt = 0; tt < 128; ++tt) {
    int tl = t0 + tt + 15;
    win[30] = (tl < T_) ? b2f(A2in[rowbase + (long)tl * K2_]) : 0.f;
    float s = 0.f;
    #pragma unroll
    for (int k = 0; k < KW_; ++k) s = fmaf(wk[k], win[k], s);
    A2out[((long)b * T_ + t0 + tt) * K2_ + c] = f2bf(s);
    #pragma unroll
    for (int k = 0; k < 30; ++k) win[k] = win[k + 1];
  }
}

// ---------------------------------------------------------------------------
// 128x128 bf16 GEMM, arithmetic-intensity-balanced: 4 waves (2Mx2N), per-wave
// 64x64 output (acc[4][4]) -> 32 FLOP per LDS byte (vs 21.3 at 64x32) --
// lifts the LDS-BW cap on MfmaUtil from ~44% to ~67%.
// BK=32, double-buffered 32KB LDS -> 4 blocks/CU (16 waves, 4/SIMD).
// 64B LDS rows -> only 2-way bank aliasing (free, m136) -> NO swizzle.
// 4 phases / 2 K-tiles; same-phase reads (compiler emits counted lgkm).
// Region-disjoint stage slots (iter i; kt1=2i+1, kt2=2i+2, kt3=2i+3):
//   P1: B1<-kt1 | P2: A0<-kt2, VMW(2) | P3: B0<-kt2 | P4: A1<-kt3, VMW(2)
// Reads: P1: buf0-A + buf0-B(n01); P2: buf0-B(n23); P3: buf1-A+B(n01);
//        P4: buf1-B(n23).  Each stage writes a region not read this phase,
// and after the last reader's closing barrier. VMW audit (2 loads/slot):
// @P2 outstanding {A1'(2),B1(2),A0(2)} -> VMW(2) retires A1',B1 = P3 deps;
// @P4 outstanding {A0(2),B0(2),A1(2)} -> retires A0,B0 = next-P1 deps;
// barrier follows each VMW before the dependent reads -> cross-wave safe.
// Prologue: A0,B0 <- t0, A1 <- t1 (6 loads), VMW(2). Tail: B1@P1, VMW(0)@P2.

// stage one 128x32 region (8KB): 2 x (256 thr x 16B)
#define ST_R(GP, GR0, BUFS, REG, KT) do { \
    _Pragma("unroll") \
    for (int i = 0; i < 2; ++i) { \
      int d = i * 4096 + tid * 16;   /* byte in 8KB region */ \
      __builtin_amdgcn_global_load_lds( \
        (GV*)(GP + (long)(GR0 + (d >> 6)) * K + (KT) * 32 + ((d & 63) >> 1)), \
        (LV*)&lds[(BUFS) + (REG) + (d >> 1)], 16, 0, 0); \
    } \
  } while (0)
#define ST_A(BUFS, KT) ST_R(A,  arow0, BUFS, 0,    KT)
#define ST_B(BUFS, KT) ST_R(Bw, brow0, BUFS, 4096, KT)

// read the wave's 4 A m-frags (one b128 each, K=32)
#define RD_A(BUFS) do { \
    _Pragma("unroll") \
    for (int mf = 0; mf < 4; ++mf) { \
      int r = wm * 64 + mf * 16 + rlane; \
      aF[mf] = *(const bf16x8*)&lds[(BUFS) + ((r * 64 + klb) >> 1)]; \
    } \
  } while (0)

// read B n-pair NP (frags n=2NP, 2NP+1)
#define RD_B(DST, BUFS, NP) do { \
    _Pragma("unroll") \
    for (int j = 0; j < 2; ++j) { \
      int r = wn * 64 + (NP) * 32 + j * 16 + rlane; \
      DST[j] = *(const bf16x8*)&lds[(BUFS) + 4096 + ((r * 64 + klb) >> 1)]; \
    } \
  } while (0)

// 8 MFMA: all 4 m-frags x n-pair NP
#define MM(BV, NP) do { \
    _Pragma("unroll") \
    for (int mf = 0; mf < 4; ++mf) \
      _Pragma("unroll") \
      for (int j = 0; j < 2; ++j) \
        acc[mf][(NP) * 2 + j] = __builtin_amdgcn_mfma_f32_16x16x32_bf16( \
            aF[mf], BV[j], acc[mf][(NP) * 2 + j], 0, 0, 0); \
  } while (0)

#define VMW(n_)  asm volatile("s_waitcnt vmcnt(" #n_ ")" ::: "memory")
#define BARO() do { asm volatile("" ::: "memory"); __builtin_amdgcn_s_barrier(); \
                    __builtin_amdgcn_s_setprio(1); } while (0)
#define BARC() do { __builtin_amdgcn_s_setprio(0); \
                    asm volatile("" ::: "memory"); __builtin_amdgcn_s_barrier(); \
                    asm volatile("" ::: "memory"); } while (0)

template<int MODE>
__global__ __launch_bounds__(256, 4) void gemm_bal(const short* __restrict__ A,
                                                   const short* __restrict__ Bw,
                                                   const float* __restrict__ bias,
                                                   void* __restrict__ Cout,
                                                   int K, int NBN, int ldo) {
  __shared__ short lds[16384];   // 32 KB: 2 bufs x (A 8KB + B 8KB)
  const int tid  = threadIdx.x;
  const int lane = tid & 63;
  const int wave = tid >> 6;     // 0..3
  const int wm = wave >> 1, wn = wave & 1;

  // bijective XCD swizzle (nwg % 8 == 0 for both GEMMs)
  const int nwg = gridDim.x;
  const int wg  = (blockIdx.x & 7) * (nwg >> 3) + (blockIdx.x >> 3);
  const int bm = wg / NBN, bn = wg % NBN;
  const int arow0 = bm * 128, brow0 = bn * 128;

  const int rlane = lane & 15;
  const int klb   = (lane >> 4) * 16;   // byte offset of lane's k-slice (64B row)

  f32x4 acc[4][4] = {};                 // 64 regs, per-wave 64x64 output
  const int nt = K >> 5;                // 32-K tiles (even, >= 4)
  const int ni = nt >> 1;               // iterations of 2 tiles (>= 2)

  bf16x8 aF[4], bF[2], bG[2];

  // prologue: A0,B0 <- t0, A1 <- t1 (6 loads); retire A0,B0, keep A1.
  ST_A(0, 0); ST_B(0, 0);
  ST_A(8192, 1);
  VMW(2);
  asm volatile("" ::: "memory"); __builtin_amdgcn_s_barrier();

  for (int i = 0; i + 1 < ni; ++i) {
    const int kt1 = 2 * i + 1, kt2 = 2 * i + 2, kt3 = 2 * i + 3;
    /*P1*/ RD_A(0);    RD_B(bF, 0, 0);    ST_B(8192, kt1);          BARO(); MM(bF, 0); BARC();
    /*P2*/ RD_B(bG, 0, 1);                ST_A(0, kt2);     VMW(2); BARO(); MM(bG, 1); BARC();
    /*P3*/ RD_A(8192); RD_B(bF, 8192, 0); ST_B(0, kt2);             BARO(); MM(bF, 0); BARC();
    /*P4*/ RD_B(bG, 8192, 1);             ST_A(8192, kt3);  VMW(2); BARO(); MM(bG, 1); BARC();
  }
  // tail iteration (tiles nt-2 in buf0, nt-1 in buf1): stage B1 only.
  /*P1*/ RD_A(0);    RD_B(bF, 0, 0);      ST_B(8192, nt - 1);       BARO(); MM(bF, 0); BARC();
  /*P2*/ RD_B(bG, 0, 1);                                    VMW(0); BARO(); MM(bG, 1); BARC();
  /*P3*/ RD_A(8192); RD_B(bF, 8192, 0);                             BARO(); MM(bF, 0); BARC();
  /*P4*/ RD_B(bG, 8192, 1);                                         BARO(); MM(bG, 1);
  __builtin_amdgcn_s_setprio(0);

  // epilogue: C/D layout col = lane&15, row = (lane>>4)*4 + i
  #pragma unroll
  for (int m = 0; m < 4; ++m) {
    const int r = arow0 + wm * 64 + m * 16 + (lane >> 4) * 4;
    #pragma unroll
    for (int n = 0; n < 4; ++n) {
      const int c = brow0 + wn * 64 + n * 16 + (lane & 15);
      if (MODE == 0) {
        const float bb = bias[c];
        #pragma unroll
        for (int i = 0; i < 4; ++i)
          ((float*)Cout)[(long)(r + i) * ldo + c] = acc[m][n][i] + bb;
      } else {
        // interleaved: even c = a_{c/2}, odd c = g_{c/2}; GLU = a*sigmoid(g)
        const int oc = (c & 1) ? (1024 + (c >> 1)) : (c >> 1);
        const float bb = bias[oc];
        #pragma unroll
        for (int i = 0; i < 4; ++i) {
          float v = acc[m][n][i] + bb;
          float o = __shfl_xor(v, 1);    // partner lane holds the paired col
          if (!(c & 1))
            ((short*)Cout)[(long)(r + i) * ldo + 1024 + (c >> 1)] =
                f2bf(v / (1.f + __expf(-o)));
        }
      }
    }
  }
}

// ---------------------------------------------------------------------------
extern "C" void kernel_launch(void* const* d_in, const int* in_sizes, int n_in,
                              void* d_out, int out_size, void* d_ws, size_t ws_size,
                              hipStream_t stream) {
  const float* q   = (const float*)d_in[0];
  const float* W1  = (const float*)d_in[4];
  const float* b1  = (const float*)d_in[5];
  const float* W2  = (const float*)d_in[6];
  const float* b2  = (const float*)d_in[7];
  const float* wt  = (const float*)d_in[8];
  const float* wtf = (const float*)d_in[9];

  // workspace layout (bf16 as short), ~104 MB total
  short* Abf = (short*)d_ws;                       // 16384x1024
  short* W1b = Abf + (long)M_ * K1_;               // 2048x1024 interleaved
  short* W2b = W1b + (long)N1_ * K1_;              // 1024x2048 (B^T for GEMM2)
  short* A2  = W2b + (long)N2_ * K2_;              // 16384x2048: [xc | x]
  float* wsm = (float*)(A2 + (long)M_ * K2_);      // 17*31 softmaxed taps

  softmax_w<<<1, 64, 0, stream>>>(wt, wtf, wsm);

  cvt_bf16<<<(M_ * K1_ / 4) / 256, 256, 0, stream>>>(q, Abf, M_ * K1_ / 4);
  cvt_w1i<<<(N1_ * K1_ / 8) / 256, 256, 0, stream>>>(W1, W1b);
  cvt_w2c<<<(C_ * C_ / 4) / 256, 256, 0, stream>>>(W2, W2b);
  fold_w2f<<<(C_ * C_) / 256, 256, 0, stream>>>(W2, wsm, W2b);

  // GEMM1 + fused GLU: x -> A2[:, 1024:2048]
  gemm_bal<1><<<(M_ / 128) * (N1_ / 128), 256, 0, stream>>>(
      Abf, W1b, b1, A2, K1_, N1_ / 128, K2_);

  // time depthwise conv -> A2[:, 0:1024]
  conv_t_k<<<dim3(T_ / 128, C_ / 256, B_), 256, 0, stream>>>(A2, wsm, A2);

  // GEMM2: out = A2 @ W2b^T + b2 -> fp32
  gemm_bal<0><<<(M_ / 128) * (N2_ / 128), 256, 0, stream>>>(
      A2, W2b, b2, d_out, K2_, N2_ / 128, N2_);
}